// Round 2
// baseline (203.474 us; speedup 1.0000x reference)
//
#include <hip/hip_runtime.h>
#include <hip/hip_bf16.h>

// Problem constants (from reference)
#define B_   256
#define M_   64
#define T_   1200
#define FT_  10
#define K_   17
#define PAD_ 8
#define POOLK_ 75
#define POOLS_ 15
#define TP_  76            // pooled length
#define NCH_ 240           // 5-output chunks per row (1200/5)
#define NSEG_ 80           // 15-output segments per row
#define FEAT_ (FT_*TP_)    // 760

// LDS layout:
//   xs   : padded row, 1216 floats
//   C5   : per-(f,chunk) sum of squares, 10*240
//   S15  : per-(f,segment) sums, 10*80
__global__ __launch_bounds__(256, 4)
void ChannelScorer_Distributed_39024072851482_kernel(
    const float* __restrict__ x,      // (B,1,M,T) -> (B*M, T)
    const float* __restrict__ conv_w, // (FT,1,K) = 170
    const float* __restrict__ conv_b, // (FT,)
    const float* __restrict__ lin_w,  // (M, FEAT)
    const float* __restrict__ lin_b,  // (M,)
    float* __restrict__ out)          // (B,M,1)
{
    __shared__ float xs[T_ + 2*PAD_];      // 1216
    __shared__ float C5[FT_ * NCH_];       // 2400
    __shared__ float S15[FT_ * NSEG_];     // 800
    __shared__ float red[4];

    const int row = blockIdx.x;            // b*M_ + m
    const int m   = row & (M_-1);
    const int tid = threadIdx.x;

    // ---- stage x row into LDS, zero-padded ----
    if (tid < PAD_)        xs[tid] = 0.f;
    if (tid >= 256 - PAD_) xs[tid + (T_ + 2*PAD_ - 256)] = 0.f;  // 1208..1215
    {
        const float4* xr = (const float4*)(x + (size_t)row * T_);
        for (int i = tid; i < T_/4; i += 256)
            *(float4*)&xs[PAD_ + 4*i] = xr[i];
    }
    __syncthreads();

    // ---- phase B: one 5-output chunk per thread, all 10 filters ----
    // chunk c covers conv outputs [5c, 5c+5); window = xs[5c .. 5c+20]
    if (tid < NCH_) {
        float xw[21];
        const int base = 5 * tid;
        #pragma unroll
        for (int j = 0; j < 21; ++j) xw[j] = xs[base + j];

        for (int f = 0; f < FT_; ++f) {       // f is wave-uniform -> s_load weights
            float wf[K_];
            #pragma unroll
            for (int k = 0; k < K_; ++k) wf[k] = conv_w[f*K_ + k];
            const float bf = conv_b[f];

            float a0 = bf, a1 = bf, a2 = bf, a3 = bf, a4 = bf;
            #pragma unroll
            for (int k = 0; k < K_; ++k) {
                const float w = wf[k];
                a0 = fmaf(xw[k    ], w, a0);
                a1 = fmaf(xw[k + 1], w, a1);
                a2 = fmaf(xw[k + 2], w, a2);
                a3 = fmaf(xw[k + 3], w, a3);
                a4 = fmaf(xw[k + 4], w, a4);
            }
            float cs = a0*a0;
            cs = fmaf(a1, a1, cs);
            cs = fmaf(a2, a2, cs);
            cs = fmaf(a3, a3, cs);
            cs = fmaf(a4, a4, cs);
            C5[f*NCH_ + tid] = cs;
        }
    }
    __syncthreads();

    // ---- phase C: segment sums S15[f][g] = sum of 3 chunk sums ----
    for (int i = tid; i < FT_*NSEG_; i += 256) {
        const int f = i / NSEG_;
        const int g = i - f*NSEG_;
        const float* c = &C5[f*NCH_ + 3*g];
        S15[i] = c[0] + c[1] + c[2];
    }
    __syncthreads();

    // ---- phase D: pooled -> log -> dot with lin_w[m,:] ----
    float partial = 0.f;
    const float* lw = lin_w + m * FEAT_;
    for (int i = tid; i < FEAT_; i += 256) {
        const int f = i / TP_;
        const int p = i - f*TP_;
        const float* s = &S15[f*NSEG_ + p];
        float v = (s[0] + s[1] + s[2] + s[3] + s[4]) * (1.0f/POOLK_);
        v = fmaxf(v, 1e-10f);
        partial = fmaf(__logf(v), lw[i], partial);
    }

    // ---- block reduction ----
    #pragma unroll
    for (int off = 32; off > 0; off >>= 1)
        partial += __shfl_down(partial, off, 64);
    const int wave = tid >> 6, lane = tid & 63;
    if (lane == 0) red[wave] = partial;
    __syncthreads();
    if (tid == 0)
        out[row] = red[0] + red[1] + red[2] + red[3] + lin_b[m];
}

extern "C" void kernel_launch(void* const* d_in, const int* in_sizes, int n_in,
                              void* d_out, int out_size, void* d_ws, size_t ws_size,
                              hipStream_t stream) {
    const float* x      = (const float*)d_in[0];
    const float* conv_w = (const float*)d_in[1];
    const float* conv_b = (const float*)d_in[2];
    const float* lin_w  = (const float*)d_in[3];
    const float* lin_b  = (const float*)d_in[4];
    float* out = (float*)d_out;

    dim3 grid(B_ * M_);
    dim3 block(256);
    ChannelScorer_Distributed_39024072851482_kernel<<<grid, block, 0, stream>>>(
        x, conv_w, conv_b, lin_w, lin_b, out);
}